// Round 16
// baseline (369.310 us; speedup 1.0000x reference)
//
#include <hip/hip_runtime.h>
#include <cstdint>
#include <cstddef>

#define TSTEPS 512
#define INP    24
#define HID    128
#define BB     4      // batch elems per block; 256 blocks (1/CU)
#define NKT    5      // K = 128 h + 24 x + 8 pad = 160 = 5 tiles of 32
#define VSTR   168    // v_s column stride in fp16 elems: [h 0..127 | x 128..151 | pad]
#define NTHR   576    // 8 compute waves + 1 dedicated staging wave

typedef __attribute__((ext_vector_type(8))) _Float16 half8;   // 8 x fp16 (4 VGPRs)
typedef __attribute__((ext_vector_type(4))) float f32x4;

__device__ __forceinline__ float rcp_f(float v) { return __builtin_amdgcn_rcpf(v); }
__device__ __forceinline__ float sigm_f(float v) {
    return rcp_f(1.0f + __expf(-v));
}
__device__ __forceinline__ float tanh_f(float v) {
    return 1.0f - 2.0f * rcp_f(1.0f + __expf(2.0f * v));
}
__device__ __forceinline__ unsigned pack2h(float a, float b) {
    union { _Float16 h[2]; unsigned u; } z;
    z.h[0] = (_Float16)a; z.h[1] = (_Float16)b;   // v_cvt_f16_f32, RTN
    return z.u;
}
// select a[r] with r = 2*rb1 + rb0; compile-time component indices (R2-safe)
__device__ __forceinline__ float sel4(const f32x4 a, bool rb0, bool rb1) {
    const float lo = rb0 ? a[1] : a[0];
    const float hi = rb0 ? a[3] : a[2];
    return rb1 ? hi : lo;
}

// ROUND LESSONS ENCODED:
//  R1: VGPR-cap betrayal -> per-ts scratch spill = WRITE_SIZE GBs. One-time
//      MBs = setup spill, benign.
//  R2: runtime-varying index into per-thread arrays demotes to memory.
//  R3: fp32 VALU ~3x too slow; use MFMA.
//  R4/R5: total time == per-block time. MINIMIZE BLOCK WALL (= max over waves).
//  R6: mfma issue 19.4 cyc/SIMD; 160 mfma/block/ts -> 776 cyc/SIMD floor,
//      irreducible at fp16/BB=4 (any reshape doubles it -- R14/R20 math).
//  R8: LDS pipe is PER-CU (40 b128/ts = ~320-480 cyc service incl 161
//      measured conflict cyc).
//  R9: fp16 single-pass; absmax ~2^-11.
//  R10: wave-local redistribution, ONE barrier/ts: 619->542us.
//  R11/R12/R13: occupancy attrs spill; HW won't co-schedule 2 blocks/CU.
//  R14: phases SUM within a wave.  R15: keep elementwise on all 64 lanes.
//  R16: bias->C-init + rcp sigm/tanh: 542->453us.
//  R17: exec-masked B-reads regressed; LDS pipe NOT critical path.
//  R18: replica columns -> redistribution = 12 cndmask: ->403us.
//  R19: uniform wave paths + dedicated stager: ->337us (rocprof).
//  R20: 1 wave/SIMD exposes all latency; 2 waves/SIMD ARE the hiding.
//  R21: x-frag across barrier + x-mfma in read window + setprio: ->312us.
//      BEST. kt-major = 4 indep chains/wave = correct mfma ILP.
//  R22: full-x LDS cache: 347us regression. Don't restructure slack.
//  R23: gate-major chains: 322us regression. Dependent 5-chains starve
//      the matrix pipe (2 chains x 19.4 < 40cyc dep latency). Source
//      tricks that cut mfma ILP lose more than the early tails gain.
//  R24 (this): R21 RESTORED + WAVE-STAGGERED LDS ISSUE. Odd waves issue
//      their 4 x-mfmas BEFORE their 5 ds_reads (x-frag in regs, no dep;
//      sched_barrier(0) pins order); even waves keep R21 order. Halves
//      the instantaneous post-barrier LDS burst: odd waves feed the
//      matrix pipe ~78cyc while even waves' reads are served, then swap.
//      Arithmetic identical -> absmax 0.0004882812. Predict rocprof
//      295-310. Falsifier: ~312 -> declare practical roofline (776 issue
//      floor + ~600 irreducible chain).
//
// Per ts: gates[512 x 4] = W[512 x 160] @ v[160 x 4], broadcast to 16 cols.
// mfma_f32_16x16x32_f16:
//   A-frag: lane holds A[m=lane&15][k=quad*8+j]
//   B-frag: lane holds B[k=quad*8+j][n=lane&15]
//   C/D:    col=lane&15, row=quad*4+reg
__global__ __launch_bounds__(NTHR)
void lstm_fused(
    const float* __restrict__ x,      // [B, T, 24]
    const float* __restrict__ addin,  // [B, 2]
    const float* __restrict__ W_ih,   // [512, 24]
    const float* __restrict__ W_hh,   // [512, 128]
    const float* __restrict__ b_ih,   // [512]
    const float* __restrict__ b_hh,   // [512]
    const float* __restrict__ W1,     // [64, 130]
    const float* __restrict__ b1,     // [64]
    const float* __restrict__ W2,     // [3, 64]
    const float* __restrict__ b2,     // [3]
    float* __restrict__ out)          // [B, 3]
{
    __shared__ _Float16 v_s[2][BB * VSTR];   // [buf][col<4][k']; k'<128 h, 128..151 x
    __shared__ float z_s[BB][64];

    const int t    = threadIdx.x;      // 576 threads = 9 waves
    const int lane = t & 63;
    const int wv   = t >> 6;           // 0..8; wave 8 = stager
    const bool is_stage = (wv == 8);
    const int ncol = lane & 15;
    const int quad = lane >> 4;
    const int b0   = blockIdx.x * BB;
    const int bsel = ncol & 3;         // broadcast source col = this lane's batch
    const bool rb0 = (ncol >> 2) & 1;  // reg-select bits: r = ncol>>2
    const bool rb1 = (ncol >> 3) & 1;

    // staging-wave role: lane sb = lane/12 (batch col), kk (k-pair); 48 active
    const int sb = lane / 12;
    const int kk = lane - sb * 12;
    const size_t xrow = (size_t)(b0 + (sb & 3)) * TSTEPS;

    // ---- init: zero both buffers (B1) ----
    for (int i = t; i < 2 * BB * VSTR; i += NTHR) {
        (&v_s[0][0])[i] = (_Float16)0.0f;
    }
    __syncthreads();   // B1

    if (is_stage) {
        // ============ STAGING WAVE (never touches W) ============
        float2 xq = {0.f, 0.f};
        if (lane < 48) {
            const float2 x0 = *(const float2*)(x + (xrow + 0) * INP + kk * 2);
            const float2 x1 = *(const float2*)(x + (xrow + 1) * INP + kk * 2);
            *(unsigned*)&v_s[0][sb * VSTR + HID + kk * 2] = pack2h(x0.x, x0.y);
            *(unsigned*)&v_s[1][sb * VSTR + HID + kk * 2] = pack2h(x1.x, x1.y);
            xq = *(const float2*)(x + (xrow + 2) * INP + kk * 2);
        }
        __syncthreads();   // B2: x(0),x(1) visible to compute waves
        __syncthreads();   // B3: compute waves captured buf0 x-region
        for (int ts = 0; ts < TSTEPS; ++ts) {
            const int pb = ts & 1;
            if (lane < 48) {
                const int tsn = (ts + 3 < TSTEPS) ? ts + 3 : TSTEPS - 1;
                const float2 xn = *(const float2*)(x + (xrow + tsn) * INP + kk * 2);
                *(unsigned*)&v_s[pb][sb * VSTR + HID + kk * 2] = pack2h(xq.x, xq.y);
                xq = xn;
            }
            __syncthreads();
        }
    } else {
        // ============ COMPUTE WAVES ============
        // persistent A-fragments (fp16), k' layout: [W_hh | W_ih | 0]
        half8 A_w[4][NKT];
        #pragma unroll
        for (int g = 0; g < 4; ++g) {
            const int row = g * HID + wv * 16 + ncol;
            #pragma unroll
            for (int kt = 0; kt < NKT; ++kt) {
                half8 frag;
                #pragma unroll
                for (int j = 0; j < 8; ++j) {
                    const int k = kt * 32 + quad * 8 + j;
                    float w = 0.0f;
                    if (k < HID)            w = W_hh[row * HID + k];
                    else if (k < HID + INP) w = W_ih[row * INP + (k - HID)];
                    frag[j] = (_Float16)w;
                }
                A_w[g][kt] = frag;
            }
        }
        // bias as mfma C-init
        f32x4 biasv[4];
        #pragma unroll
        for (int g = 0; g < 4; ++g) {
            #pragma unroll
            for (int r = 0; r < 4; ++r) {
                const int u = wv * 16 + quad * 4 + r;
                biasv[g][r] = b_ih[g * HID + u] + b_hh[g * HID + u];
            }
        }
        const int uj = wv * 16 + quad * 4 + (ncol >> 2);
        float c_reg = 0.0f;
        const bool odd = (wv & 1) != 0;

        __syncthreads();   // B2: x(0), x(1) staged

        // capture x(0) fragment into regs (survives stager's overwrite)
        half8 bxh = *(const half8*)(&v_s[0][0] + bsel * VSTR + HID + quad * 8);
        __syncthreads();   // B3: stager may now overwrite buf0 x-region

        #pragma unroll 2
        for (int ts = 0; ts < TSTEPS; ++ts) {
            const int pb = ts & 1, nb = pb ^ 1;
            const _Float16* vh = v_s[pb];

            half8 bh0, bh1, bh2, bh3, bxn;
            f32x4 aci, acf, acg, aco;

            if (odd) {
                // odd waves: x-mfma FIRST (feeds matrix pipe while even
                // waves' reads are served), then reads
                aci = __builtin_amdgcn_mfma_f32_16x16x32_f16(A_w[0][4], bxh, biasv[0], 0, 0, 0);
                acf = __builtin_amdgcn_mfma_f32_16x16x32_f16(A_w[1][4], bxh, biasv[1], 0, 0, 0);
                acg = __builtin_amdgcn_mfma_f32_16x16x32_f16(A_w[2][4], bxh, biasv[2], 0, 0, 0);
                aco = __builtin_amdgcn_mfma_f32_16x16x32_f16(A_w[3][4], bxh, biasv[3], 0, 0, 0);
                __builtin_amdgcn_sched_barrier(0);   // pin: mfmas before reads
                bh0 = *(const half8*)(vh + bsel * VSTR + 0 * 32 + quad * 8);
                bh1 = *(const half8*)(vh + bsel * VSTR + 1 * 32 + quad * 8);
                bh2 = *(const half8*)(vh + bsel * VSTR + 2 * 32 + quad * 8);
                bh3 = *(const half8*)(vh + bsel * VSTR + 3 * 32 + quad * 8);
                bxn = *(const half8*)(&v_s[nb][0] + bsel * VSTR + HID + quad * 8);
            } else {
                // even waves: R21 order (reads first, x-mfma in the window)
                bh0 = *(const half8*)(vh + bsel * VSTR + 0 * 32 + quad * 8);
                bh1 = *(const half8*)(vh + bsel * VSTR + 1 * 32 + quad * 8);
                bh2 = *(const half8*)(vh + bsel * VSTR + 2 * 32 + quad * 8);
                bh3 = *(const half8*)(vh + bsel * VSTR + 3 * 32 + quad * 8);
                bxn = *(const half8*)(&v_s[nb][0] + bsel * VSTR + HID + quad * 8);
                aci = __builtin_amdgcn_mfma_f32_16x16x32_f16(A_w[0][4], bxh, biasv[0], 0, 0, 0);
                acf = __builtin_amdgcn_mfma_f32_16x16x32_f16(A_w[1][4], bxh, biasv[1], 0, 0, 0);
                acg = __builtin_amdgcn_mfma_f32_16x16x32_f16(A_w[2][4], bxh, biasv[2], 0, 0, 0);
                aco = __builtin_amdgcn_mfma_f32_16x16x32_f16(A_w[3][4], bxh, biasv[3], 0, 0, 0);
            }

            // h-GEMM: kt-major, 4 independent chains (R21 exact)
            __builtin_amdgcn_s_setprio(1);
            f32x4 ai = __builtin_amdgcn_mfma_f32_16x16x32_f16(A_w[0][0], bh0, aci, 0, 0, 0);
            f32x4 af = __builtin_amdgcn_mfma_f32_16x16x32_f16(A_w[1][0], bh0, acf, 0, 0, 0);
            f32x4 ag = __builtin_amdgcn_mfma_f32_16x16x32_f16(A_w[2][0], bh0, acg, 0, 0, 0);
            f32x4 ao = __builtin_amdgcn_mfma_f32_16x16x32_f16(A_w[3][0], bh0, aco, 0, 0, 0);
            ai = __builtin_amdgcn_mfma_f32_16x16x32_f16(A_w[0][1], bh1, ai, 0, 0, 0);
            af = __builtin_amdgcn_mfma_f32_16x16x32_f16(A_w[1][1], bh1, af, 0, 0, 0);
            ag = __builtin_amdgcn_mfma_f32_16x16x32_f16(A_w[2][1], bh1, ag, 0, 0, 0);
            ao = __builtin_amdgcn_mfma_f32_16x16x32_f16(A_w[3][1], bh1, ao, 0, 0, 0);
            ai = __builtin_amdgcn_mfma_f32_16x16x32_f16(A_w[0][2], bh2, ai, 0, 0, 0);
            af = __builtin_amdgcn_mfma_f32_16x16x32_f16(A_w[1][2], bh2, af, 0, 0, 0);
            ag = __builtin_amdgcn_mfma_f32_16x16x32_f16(A_w[2][2], bh2, ag, 0, 0, 0);
            ao = __builtin_amdgcn_mfma_f32_16x16x32_f16(A_w[3][2], bh2, ao, 0, 0, 0);
            ai = __builtin_amdgcn_mfma_f32_16x16x32_f16(A_w[0][3], bh3, ai, 0, 0, 0);
            af = __builtin_amdgcn_mfma_f32_16x16x32_f16(A_w[1][3], bh3, af, 0, 0, 0);
            ag = __builtin_amdgcn_mfma_f32_16x16x32_f16(A_w[2][3], bh3, ag, 0, 0, 0);
            ao = __builtin_amdgcn_mfma_f32_16x16x32_f16(A_w[3][3], bh3, ao, 0, 0, 0);
            __builtin_amdgcn_s_setprio(0);

            // in-register redistribution + cell update (all 64 lanes)
            const float si = sel4(ai, rb0, rb1);
            const float sf = sel4(af, rb0, rb1);
            const float sg = sel4(ag, rb0, rb1);
            const float so = sel4(ao, rb0, rb1);
            {
                const float gi = sigm_f(si);
                const float gf = sigm_f(sf);
                const float gg = tanh_f(sg);
                const float go = sigm_f(so);
                c_reg = gf * c_reg + gi * gg;
                const float h = go * tanh_f(c_reg);
                v_s[nb][bsel * VSTR + uj] = (_Float16)h;
            }

            // roll held x-frag
            bxh = bxn;

            // single cross-wave hazard: h(ts) + x(ts+2) visible next epoch
            __syncthreads();
        }
    }

    // ---- FC head: final h is in buffer 0 (ts=511 -> nb=0), offset 0..127 ----
    if (t < 64 * BB) {
        const int b = t >> 6, u = t & 63;
        const float* w = W1 + u * 130;
        float a = b1[u];
        #pragma unroll 16
        for (int k = 0; k < HID; ++k) {
            const float hv = (float)v_s[0][b * VSTR + k];
            a += fmaxf(hv, 0.0f) * w[k];
        }
        const float a0 = addin[(size_t)(b0 + b) * 2 + 0];
        const float a1 = addin[(size_t)(b0 + b) * 2 + 1];
        a += fmaxf(a0, 0.0f) * w[128] + fmaxf(a1, 0.0f) * w[129];
        z_s[b][u] = fmaxf(a, 0.0f);
    }
    __syncthreads();
    if (t < 3 * BB) {
        const int b = t / 3, o = t - 3 * b;
        const float* w = W2 + o * 64;
        float a = b2[o];
        #pragma unroll
        for (int k = 0; k < 64; ++k)
            a += z_s[b][k] * w[k];
        out[(size_t)(b0 + b) * 3 + o] = a;
    }
}

extern "C" void kernel_launch(void* const* d_in, const int* in_sizes, int n_in,
                              void* d_out, int out_size, void* d_ws, size_t ws_size,
                              hipStream_t stream) {
    const float* x     = (const float*)d_in[0];
    const float* addin = (const float*)d_in[1];
    const float* W_ih  = (const float*)d_in[2];
    const float* W_hh  = (const float*)d_in[3];
    const float* b_ih  = (const float*)d_in[4];
    const float* b_hh  = (const float*)d_in[5];
    const float* W1    = (const float*)d_in[6];
    const float* b1    = (const float*)d_in[7];
    const float* W2    = (const float*)d_in[8];
    const float* b2    = (const float*)d_in[9];
    float* outp        = (float*)d_out;

    const int B = in_sizes[0] / (TSTEPS * INP);   // 1024
    const int grid = B / BB;                      // 256 blocks (1 per CU)

    lstm_fused<<<grid, NTHR, 0, stream>>>(x, addin, W_ih, W_hh, b_ih, b_hh,
                                          W1, b1, W2, b2, outp);
}